// Round 1
// baseline (205.134 us; speedup 1.0000x reference)
//
#include <hip/hip_runtime.h>
#include <cstdint>
#include <cstddef>

#define HW 524288      // H*W = 512*1024
#define NBIN 2048      // lovasz error histogram bins over [0,2]

// ws layout (bytes):
//   0      : double acc[2][8][8]  {cnt,cx,cy,sx,sy,sxx,syy,seedfg}   1024 B
//   1024   : double seedbg[2]                                          16 B
//   1040   : float  lov[16]                                            64 B
//   4096   : u32    ghist[16][NBIN][2]                             262144 B
// memset range: [0, 266240)

__device__ __forceinline__ float wred(float v) {
#pragma unroll
  for (int o = 32; o > 0; o >>= 1) v += __shfl_xor(v, o, 64);
  return v;
}

__device__ __forceinline__ float fsig(float x) {
  return __builtin_amdgcn_rcpf(1.f + expf(-x));
}

// ---------------- pass1: masked per-instance sums + seed_bg ----------------
__global__ __launch_bounds__(256) void pass1(
    const float* __restrict__ pred, const int* __restrict__ bbox,
    const int* __restrict__ masks, double* __restrict__ acc,
    double* __restrict__ seedbg)
{
  const int b = blockIdx.y;
  const int tid = threadIdx.x;
  const int chunk = blockIdx.x;                 // 256 chunks of 2048 px
  const float* pb = pred + (size_t)b * 12 * HW;
  const int*   mk = masks + (size_t)b * 8 * HW;
  const int*   bb = bbox  + (size_t)b * 9 * HW + HW;  // channels 1..8

  float c[8] = {0}, cx[8] = {0}, cy[8] = {0}, sx[8] = {0}, sy[8] = {0},
        sxx[8] = {0}, syy[8] = {0};
  float sbg = 0.f;

#pragma unroll
  for (int k = 0; k < 8; k++) {
    int idx = chunk * 2048 + k * 256 + tid;
    int h = idx >> 10, w = idx & 1023;
    float p0 = pb[idx], p1 = pb[HW + idx];
    float ex = tanhf(p0) + (float)(w * (2.0 / 2047.0));
    float ey = tanhf(p1) + (float)(h * (1.0 / 1023.0));
    float s0 = pb[2 * HW + idx], s1 = pb[3 * HW + idx];
#pragma unroll
    for (int n = 0; n < 8; n++) {
      float mf = (mk[n * HW + idx] > 0) ? 1.f : 0.f;
      c[n] += mf; cx[n] += mf * ex; cy[n] += mf * ey;
      sx[n] += mf * s0; sy[n] += mf * s1;
      sxx[n] += mf * s0 * s0; syy[n] += mf * s1 * s1;
    }
#pragma unroll
    for (int cc = 0; cc < 8; cc++) {
      float sv = pb[(4 + cc) * HW + idx];
      int bv = bb[cc * HW + idx];
      float sg = fsig(sv);
      sbg += (bv == 0) ? sg * sg : 0.f;
    }
  }

  __shared__ float red[4][57];
  int lane = tid & 63, wid = tid >> 6;
#pragma unroll
  for (int n = 0; n < 8; n++) {
    float r0 = wred(c[n]),  r1 = wred(cx[n]), r2 = wred(cy[n]),
          r3 = wred(sx[n]), r4 = wred(sy[n]), r5 = wred(sxx[n]),
          r6 = wred(syy[n]);
    if (lane == 0) {
      red[wid][n * 7 + 0] = r0; red[wid][n * 7 + 1] = r1;
      red[wid][n * 7 + 2] = r2; red[wid][n * 7 + 3] = r3;
      red[wid][n * 7 + 4] = r4; red[wid][n * 7 + 5] = r5;
      red[wid][n * 7 + 6] = r6;
    }
  }
  { float r = wred(sbg); if (lane == 0) red[wid][56] = r; }
  __syncthreads();
  if (tid < 57) {
    float s = red[0][tid] + red[1][tid] + red[2][tid] + red[3][tid];
    if (tid < 56) {
      int n = tid / 7, q = tid % 7;
      atomicAdd(&acc[((size_t)b * 8 + n) * 8 + q], (double)s);
    } else {
      atomicAdd(&seedbg[b], (double)s);
    }
  }
}

// ------- pass3: per-(b,n) dist, seed_fg, lovasz-error LDS histogram -------
__global__ __launch_bounds__(1024) void pass3(
    const float* __restrict__ pred, const int* __restrict__ masks,
    const int* __restrict__ cls_ids, double* __restrict__ acc,
    unsigned* __restrict__ ghist)
{
  const int seg = blockIdx.y;                 // 0..15 = b*8+n
  const int b = seg >> 3, n = seg & 7;
  const int tid = threadIdx.x;
  __shared__ unsigned hist[NBIN * 2];
  __shared__ float red[16];
  for (int j = tid; j < NBIN * 2; j += 1024) hist[j] = 0;

  const double* a = acc + seg * 8;
  double cntd = a[0];
  double cs = cntd < 1.0 ? 1.0 : cntd;
  float cxv = (float)(a[1] / cs), cyv = (float)(a[2] / cs);
  float sex = expf((float)(a[3] / cs) * 10.f);
  float sey = expf((float)(a[4] / cs) * 10.f);
  int cls = cls_ids[b * 8 + n];
  const float* pb = pred + (size_t)b * 12 * HW;
  const float* seedp = pb + (size_t)(4 + cls) * HW;
  const int* mp = masks + (size_t)seg * HW;
  __syncthreads();

  float sf = 0.f;
  int base = blockIdx.x * 32768;
#pragma unroll 4
  for (int i = 0; i < 32; i++) {
    int idx = base + i * 1024 + tid;
    float p0 = pb[idx], p1 = pb[HW + idx];
    int m = (mp[idx] > 0) ? 1 : 0;
    float sv = seedp[idx];
    int h = idx >> 10, w = idx & 1023;
    float ex = tanhf(p0) + (float)(w * (2.0 / 2047.0));
    float ey = tanhf(p1) + (float)(h * (1.0 / 1023.0));
    float dx = ex - cxv, dy = ey - cyv;
    float d = expf(-(dx * dx * sex + dy * dy * sey));
    float sg = fsig(sv);
    float df = sg - d;
    sf += m ? df * df : 0.f;
    float e = m ? 2.f - 2.f * d : 2.f * d;
    int k = (int)(e * 1024.f); k = k > (NBIN - 1) ? (NBIN - 1) : k;
    atomicAdd(&hist[k * 2 + m], 1u);
  }
  __syncthreads();

  unsigned* gh = ghist + (size_t)seg * NBIN * 2;
  for (int j = tid; j < NBIN * 2; j += 1024) {
    unsigned v = hist[j];
    if (v) atomicAdd(&gh[j], v);
  }

  float r = wred(sf);
  int lane = tid & 63, wid = tid >> 6;
  if (lane == 0) red[wid] = r;
  __syncthreads();
  if (tid == 0) {
    float t = 0.f;
    for (int w2 = 0; w2 < 16; w2++) t += red[w2];
    atomicAdd(&acc[seg * 8 + 7], (double)t);
  }
}

// ------- pass4: closed-form Lovász over descending histogram bins -------
// positive run at start (p,C): each grad = 1/(G+p-C)
// negative run of n0 at (p,C): sum grad = (G-C)*(1/a - 1/(a+n0)), a=G+p-C
__global__ __launch_bounds__(64) void pass4(
    const unsigned* __restrict__ ghist, const double* __restrict__ acc,
    float* __restrict__ lov)
{
  int seg = blockIdx.x;
  int lane = threadIdx.x;
  const unsigned* gh = ghist + (size_t)seg * NBIN * 2;
  double G = acc[seg * 8 + 0];

  unsigned cntT = 0, posT = 0;
#pragma unroll
  for (int i = 0; i < 32; i++) {
    int kk = (NBIN - 1) - lane * 32 - i;     // descending error
    unsigned h1 = gh[kk * 2 + 1], h0 = gh[kk * 2 + 0];
    cntT += h1 + h0; posT += h1;
  }
  // exclusive scan over lanes (lane 0 = highest errors = first positions)
  unsigned ic = cntT, ip = posT;
  for (int o = 1; o < 64; o <<= 1) {
    unsigned yc = __shfl_up(ic, o, 64), yp = __shfl_up(ip, o, 64);
    if (lane >= o) { ic += yc; ip += yp; }
  }
  unsigned p = ic - cntT, C = ip - posT;

  double S = 0.0;
  for (int i = 0; i < 32; i++) {
    int kk = (NBIN - 1) - lane * 32 - i;
    unsigned n1 = gh[kk * 2 + 1], n0 = gh[kk * 2 + 0];
    double ec = (kk + 0.5) * (1.0 / 1024.0);   // bin-center error value
    if (n1) {
      S += (double)n1 * ec / (G + (double)(p - C));
      p += n1; C += n1;
    }
    if (n0) {
      double rem = G - (double)C;
      if (rem > 0.0) {
        double aa = rem + (double)(p - C) + (double)C - (double)C + (double)p - (double)p; // keep simple below
        aa = G + (double)(p - C);
        S += ec * rem * (1.0 / aa - 1.0 / (aa + (double)n0));
      }
      p += n0;
    }
  }
#pragma unroll
  for (int o = 32; o > 0; o >>= 1) S += __shfl_xor(S, o, 64);
  if (lane == 0) lov[seg] = (float)S;
}

// ---------------- pass5: combine to scalar loss ----------------
__global__ void pass5(const double* __restrict__ acc,
                      const double* __restrict__ seedbg,
                      const float* __restrict__ lov,
                      const int* __restrict__ cls_ids,
                      float* __restrict__ out)
{
  __shared__ double lval[16], vval[16], sval[16];
  __shared__ float valv[16];
  int t = threadIdx.x;
  const float FG[8] = {10.f, 10.f, 10.f, 40.f, 80.f, 100.f, 60.f, 20.f};
  if (t < 16) {
    const double* a = acc + t * 8;
    double cnt = a[0];
    double cs = cnt < 1.0 ? 1.0 : cnt;
    double smx = a[3] / cs, smy = a[4] / cs;
    double var = ((a[5] - cnt * smx * smx) + (a[6] - cnt * smy * smy)) / (2.0 * cs);
    lval[t] = (double)lov[t];
    vval[t] = var;
    sval[t] = (double)FG[cls_ids[t]] * a[7];
    valv[t] = (cnt >= 128.0) ? 1.f : 0.f;
  }
  __syncthreads();
  if (t == 0) {
    double total = 0.0;
    for (int b = 0; b < 2; b++) {
      double obj = 0, inst = 0, varl = 0, sfg = 0;
      for (int n = 0; n < 8; n++) {
        int s = b * 8 + n;
        double v = (double)valv[s];
        obj += v; inst += lval[s] * v; varl += vval[s] * v; sfg += sval[s] * v;
      }
      double objs = obj < 1.0 ? 1.0 : obj;
      double seedl = (seedbg[b] + sfg) / (double)HW;
      total += inst / objs + 10.0 * (varl / objs) + seedl;
    }
    out[0] = (float)(0.5 * total);
  }
}

extern "C" void kernel_launch(void* const* d_in, const int* in_sizes, int n_in,
                              void* d_out, int out_size, void* d_ws, size_t ws_size,
                              hipStream_t stream)
{
  (void)in_sizes; (void)n_in; (void)out_size; (void)ws_size;
  const float* pred  = (const float*)d_in[0];
  const int*   bbox  = (const int*)d_in[1];
  const int*   masks = (const int*)d_in[2];
  const int*   cls   = (const int*)d_in[3];

  char* ws = (char*)d_ws;
  double*   acc    = (double*)(ws + 0);       // 128 doubles
  double*   seedbg = (double*)(ws + 1024);    // 2 doubles
  float*    lov    = (float*)(ws + 1040);     // 16 floats
  unsigned* ghist  = (unsigned*)(ws + 4096);  // 16*NBIN*2 u32

  hipMemsetAsync(d_ws, 0, 266240, stream);
  pass1<<<dim3(256, 2), 256, 0, stream>>>(pred, bbox, masks, acc, seedbg);
  pass3<<<dim3(16, 16), 1024, 0, stream>>>(pred, masks, cls, acc, ghist);
  pass4<<<16, 64, 0, stream>>>(ghist, acc, lov);
  pass5<<<1, 64, 0, stream>>>(acc, seedbg, lov, cls, (float*)d_out);
}